// Round 12
// baseline (412.928 us; speedup 1.0000x reference)
//
#include <hip/hip_runtime.h>

// ---------------------------------------------------------------------------
// Batch-inner LeNet, MFMA conv2. lane = image, activations [feature][N].
// conv2 = per-position GEMM C[16oc][N] = W[16][150] @ P[150][N] using
// mfma_f32_16x16x32_bf16 with hi/lo bf16 split (3 MFMAs ~ fp32 precision).
// conv1 writes p1 PACKED: word = (bf16_hi<<16)|bf16_lo -> conv2 loads both
// planes with one dword. Verified layouts (learn_hip m89/m91):
//   A[16x32]: row=lane&15,  k=(lane>>4)*8+j
//   B[32x16]: col=lane&15,  k=(lane>>4)*8+j
//   D[16x16]: col=lane&15, row=(lane>>4)*4+reg
// ---------------------------------------------------------------------------

typedef __attribute__((ext_vector_type(8))) short bf16x8;
typedef __attribute__((ext_vector_type(4))) float f32x4;

union PackB { uint32_t u[4]; bf16x8 v; };

__device__ __forceinline__ int xcd_swizzle(int orig, int nwg) {
    int xcd = orig & 7, q = nwg >> 3, r = nwg & 7;
    int base = (xcd < r) ? xcd * (q + 1) : r * (q + 1) + (xcd - r) * q;
    return base + (orig >> 3);
}

// pack fp32 -> (bf16_hi << 16) | bf16_lo   (v - hi residual, truncation)
__device__ __forceinline__ uint32_t pack_hilo(float v) {
    uint32_t u = __float_as_uint(v);
    uint32_t hb = u & 0xFFFF0000u;
    float lo = v - __uint_as_float(hb);
    return hb | (__float_as_uint(lo) >> 16);
}

// Transpose x[nc,784] -> xt[1024,nc] (zero-padded 32x32 image layout).
__global__ __launch_bounds__(256) void transpose_x(
    const float* __restrict__ x, float* __restrict__ xt, int nc)
{
    __shared__ float t[64][65];
    const int tx = threadIdx.x & 63, ty = threadIdx.x >> 6;
    const int p0 = blockIdx.x * 64, n0 = blockIdx.y * 64;
    #pragma unroll
    for (int rr = 0; rr < 16; ++rr) {
        int nl = rr * 4 + ty;
        int pp = p0 + tx;
        int pr = pp >> 5, pc = pp & 31;
        float v = 0.f;
        if (pr >= 2 && pr < 30 && pc >= 2 && pc < 30)
            v = x[(size_t)(n0 + nl) * 784 + (pr - 2) * 28 + (pc - 2)];
        t[tx][nl] = v;
    }
    __syncthreads();
    #pragma unroll
    for (int rr = 0; rr < 16; ++rr) {
        int pl = rr * 4 + ty;
        xt[(size_t)(p0 + pl) * nc + n0 + tx] = t[pl][tx];
    }
}

// conv1(pad2)+relu+pool, row-streaming, 2 images/thread (float2),
// 3 channels per block. Writes p1 PACKED hi/lo (uint32 per value).
__global__ __launch_bounds__(256, 2) void conv1_bt(
    const float* __restrict__ xt, const float* __restrict__ c1w,
    const float* __restrict__ c1b, uint32_t* __restrict__ p1p, int nc)
{
    const int newid = xcd_swizzle(blockIdx.x, gridDim.x);
    const int grp = newid / 392, rem = newid - grp * 392;
    const int pass = rem / 196, pos = rem - pass * 196;
    const int py = pos / 14, px = pos - py * 14;
    const int img = grp * 512 + threadIdx.x * 2;
    const float* pb = xt + (size_t)((2 * py) * 32 + 2 * px) * nc + img;

    float2 acc[12];
    #pragma unroll
    for (int i = 0; i < 12; ++i) acc[i] = make_float2(0.f, 0.f);

    #pragma unroll
    for (int r = 0; r < 6; ++r) {
        float2 row[6];
        #pragma unroll
        for (int cc = 0; cc < 6; ++cc)
            row[cc] = *(const float2*)&pb[(size_t)(r * 32 + cc) * nc];
        #pragma unroll
        for (int c3 = 0; c3 < 3; ++c3) {
            const float* wp = c1w + (pass * 3 + c3) * 25;
            if (r <= 4) {
                #pragma unroll
                for (int kx = 0; kx < 5; ++kx) {
                    float w = wp[r * 5 + kx];
                    acc[c3*4+0].x += row[kx].x   * w;
                    acc[c3*4+0].y += row[kx].y   * w;
                    acc[c3*4+1].x += row[kx+1].x * w;
                    acc[c3*4+1].y += row[kx+1].y * w;
                }
            }
            if (r >= 1) {
                #pragma unroll
                for (int kx = 0; kx < 5; ++kx) {
                    float w = wp[(r - 1) * 5 + kx];
                    acc[c3*4+2].x += row[kx].x   * w;
                    acc[c3*4+2].y += row[kx].y   * w;
                    acc[c3*4+3].x += row[kx+1].x * w;
                    acc[c3*4+3].y += row[kx+1].y * w;
                }
            }
        }
    }
    #pragma unroll
    for (int c3 = 0; c3 < 3; ++c3) {
        int ch = pass * 3 + c3;
        float b = c1b[ch];
        float mx = fmaxf(fmaxf(acc[c3*4+0].x, acc[c3*4+1].x),
                         fmaxf(acc[c3*4+2].x, acc[c3*4+3].x)) + b;
        float my = fmaxf(fmaxf(acc[c3*4+0].y, acc[c3*4+1].y),
                         fmaxf(acc[c3*4+2].y, acc[c3*4+3].y)) + b;
        uint2 o2;
        o2.x = pack_hilo(fmaxf(mx, 0.f));
        o2.y = pack_hilo(fmaxf(my, 0.f));
        *(uint2*)&p1p[(size_t)(ch * 196 + pos) * nc + img] = o2;
    }
}

// conv2 via MFMA: block = 1 quad-pos x 256 imgs (4 waves x 4 groups of 16).
// Per wave: A-frags (W hi/lo, 5 ksteps) + per-lane offset table voff[5][8]
// built once; main loop = 8 dword loads + bit-unpack + 3 MFMAs per
// (conv-pos, kstep), 4 acc chains interleaved. Pool+bias+relu epilogue.
// k = ci*25 + ky*5 + kx (padded 150->160, A zeroed, B clamped to k=149).
__global__ __launch_bounds__(256) void conv2_mfma(
    const uint32_t* __restrict__ p1p, const float* __restrict__ c2w,
    const float* __restrict__ c2b, float* __restrict__ ht, int nc)
{
    const int newid = xcd_swizzle(blockIdx.x, gridDim.x);
    const int grp = newid / 25, pos = newid - grp * 25;
    const int qy = pos / 5, qx = pos - qy * 5;
    const int wave = threadIdx.x >> 6, lane = threadIdx.x & 63;
    const int lhi = lane >> 4, llo = lane & 15;

    // ---- one-time per-wave setup ----
    uint32_t voff[5][8];
    bf16x8 wh[5], wl[5];
    #pragma unroll
    for (int s = 0; s < 5; ++s) {
        PackB ph, pl;
        #pragma unroll
        for (int j = 0; j < 8; ++j) {
            int k = s * 32 + lhi * 8 + j;
            int kc = (k < 150) ? k : 149;
            int ci = kc / 25, r = kc - ci * 25;
            int ky = r / 5, kx = r - ky * 5;
            int feat0 = ci * 196 + (2 * qy + ky) * 14 + (2 * qx + kx);
            voff[s][j] = (uint32_t)feat0 * (uint32_t)nc + wave * 16 + llo;
            float w = (k < 150) ? c2w[(llo * 6 + ci) * 25 + r] : 0.f;
            uint32_t u  = __float_as_uint(w);
            uint32_t hb = u & 0xFFFF0000u;
            float    lo = w - __uint_as_float(hb);
            uint32_t lb = __float_as_uint(lo) & 0xFFFF0000u;
            if (j & 1) { ph.u[j >> 1] |= hb;       pl.u[j >> 1] |= lb; }
            else       { ph.u[j >> 1]  = hb >> 16; pl.u[j >> 1]  = lb >> 16; }
        }
        wh[s] = ph.v; wl[s] = pl.v;
    }
    float bias[4];
    size_t rowoff[4];
    #pragma unroll
    for (int r = 0; r < 4; ++r) {
        int oc = lhi * 4 + r;
        bias[r] = c2b[oc];
        rowoff[r] = (size_t)(oc * 25 + pos) * nc;
    }

    const int imgbase = grp * 256;
    #pragma unroll 1
    for (int it = 0; it < 4; ++it) {
        f32x4 acc[4];
        #pragma unroll
        for (int p = 0; p < 4; ++p) acc[p] = (f32x4)(0.f);

        #pragma unroll
        for (int s = 0; s < 5; ++s) {
            #pragma unroll
            for (int p = 0; p < 4; ++p) {
                const uint32_t* ptr =
                    p1p + (size_t)((p >> 1) * 14 + (p & 1)) * nc
                        + imgbase + it * 64;
                uint32_t w0 = ptr[voff[s][0]], w1 = ptr[voff[s][1]];
                uint32_t w2 = ptr[voff[s][2]], w3 = ptr[voff[s][3]];
                uint32_t w4 = ptr[voff[s][4]], w5 = ptr[voff[s][5]];
                uint32_t w6 = ptr[voff[s][6]], w7 = ptr[voff[s][7]];
                PackB bh, bl;
                bh.u[0] = (w0 >> 16) | (w1 & 0xFFFF0000u);
                bh.u[1] = (w2 >> 16) | (w3 & 0xFFFF0000u);
                bh.u[2] = (w4 >> 16) | (w5 & 0xFFFF0000u);
                bh.u[3] = (w6 >> 16) | (w7 & 0xFFFF0000u);
                bl.u[0] = (w0 & 0xFFFFu) | (w1 << 16);
                bl.u[1] = (w2 & 0xFFFFu) | (w3 << 16);
                bl.u[2] = (w4 & 0xFFFFu) | (w5 << 16);
                bl.u[3] = (w6 & 0xFFFFu) | (w7 << 16);
                acc[p] = __builtin_amdgcn_mfma_f32_16x16x32_bf16(
                             wh[s], bh.v, acc[p], 0, 0, 0);
                acc[p] = __builtin_amdgcn_mfma_f32_16x16x32_bf16(
                             wh[s], bl.v, acc[p], 0, 0, 0);
                acc[p] = __builtin_amdgcn_mfma_f32_16x16x32_bf16(
                             wl[s], bh.v, acc[p], 0, 0, 0);
            }
        }
        #pragma unroll
        for (int r = 0; r < 4; ++r) {
            float m = fmaxf(fmaxf(acc[0][r], acc[1][r]),
                            fmaxf(acc[2][r], acc[3][r]));
            m = fmaxf(m + bias[r], 0.f);
            ht[rowoff[r] + imgbase + it * 64 + wave * 16 + llo] = m;
        }
    }
}

// fc1: a1t[o][n] = relu(sum_k ht[k][n]*f1w[o][k] + b). 2 img/thread.
__global__ __launch_bounds__(256) void fc1_bt(
    const float* __restrict__ ht, const float* __restrict__ f1w,
    const float* __restrict__ f1b, float* __restrict__ a1t, int nc)
{
    const int newid = xcd_swizzle(blockIdx.x, gridDim.x);
    const int grp = newid / 15, og = newid - grp * 15;
    const int img = grp * 512 + threadIdx.x * 2;
    const float* wb = f1w + og * 8 * 400;

    float2 acc[8];
    #pragma unroll
    for (int j = 0; j < 8; ++j) acc[j] = make_float2(0.f, 0.f);

    #pragma unroll 4
    for (int k = 0; k < 400; ++k) {
        float2 hv = *(const float2*)&ht[(size_t)k * nc + img];
        #pragma unroll
        for (int j = 0; j < 8; ++j) {
            float w = wb[j * 400 + k];
            acc[j].x += hv.x * w;
            acc[j].y += hv.y * w;
        }
    }
    #pragma unroll
    for (int j = 0; j < 8; ++j) {
        int o = og * 8 + j;
        float b = f1b[o];
        float2 o2 = make_float2(fmaxf(acc[j].x + b, 0.f),
                                fmaxf(acc[j].y + b, 0.f));
        *(float2*)&a1t[(size_t)o * nc + img] = o2;
    }
}

// fc2: a2t[o][n] = relu(sum_k a1t[k][n]*f2w[o][k] + b).
__global__ __launch_bounds__(256) void fc2_bt(
    const float* __restrict__ a1t, const float* __restrict__ f2w,
    const float* __restrict__ f2b, float* __restrict__ a2t, int nc)
{
    const int newid = xcd_swizzle(blockIdx.x, gridDim.x);
    const int grp = newid / 12, og = newid - grp * 12;
    const int img = grp * 512 + threadIdx.x * 2;
    const float* wb = f2w + og * 7 * 120;

    float2 acc[7];
    #pragma unroll
    for (int j = 0; j < 7; ++j) acc[j] = make_float2(0.f, 0.f);

    #pragma unroll 4
    for (int k = 0; k < 120; ++k) {
        float2 hv = *(const float2*)&a1t[(size_t)k * nc + img];
        #pragma unroll
        for (int j = 0; j < 7; ++j) {
            float w = wb[j * 120 + k];
            acc[j].x += hv.x * w;
            acc[j].y += hv.y * w;
        }
    }
    #pragma unroll
    for (int j = 0; j < 7; ++j) {
        int o = og * 7 + j;
        float b = f2b[o];
        float2 o2 = make_float2(fmaxf(acc[j].x + b, 0.f),
                                fmaxf(acc[j].y + b, 0.f));
        *(float2*)&a2t[(size_t)o * nc + img] = o2;
    }
}

// fc3 (no relu): embt[o][n0+n] = sum_k a2t[k][n]*f3w[o][k] + b.
__global__ __launch_bounds__(256) void fc3_bt(
    const float* __restrict__ a2t, const float* __restrict__ f3w,
    const float* __restrict__ f3b, float* __restrict__ embt,
    int nc, int Ntot, int n0)
{
    const int newid = xcd_swizzle(blockIdx.x, gridDim.x);
    const int grp = newid / 8, og = newid - grp * 8;
    const int limg = grp * 512 + threadIdx.x * 2;
    const float* wb = f3w + og * 8 * 84;

    float2 acc[8];
    #pragma unroll
    for (int j = 0; j < 8; ++j) acc[j] = make_float2(0.f, 0.f);

    #pragma unroll 4
    for (int k = 0; k < 84; ++k) {
        float2 hv = *(const float2*)&a2t[(size_t)k * nc + limg];
        #pragma unroll
        for (int j = 0; j < 8; ++j) {
            float w = wb[j * 84 + k];
            acc[j].x += hv.x * w;
            acc[j].y += hv.y * w;
        }
    }
    #pragma unroll
    for (int j = 0; j < 8; ++j) {
        int o = og * 8 + j;
        float b = f3b[o];
        float2 o2 = make_float2(acc[j].x + b, acc[j].y + b);
        *(float2*)&embt[(size_t)o * Ntot + n0 + limg] = o2;
    }
}

// Head: thread = image. Serial 64-wide softmax in registers.
__global__ __launch_bounds__(256) void proto_head_t(
    const float* __restrict__ embt, float* __restrict__ out, int N)
{
    const int img = blockIdx.x * 256 + threadIdx.x;
    float v[64];
    float m = -1e30f;
    #pragma unroll
    for (int o = 0; o < 64; ++o) {
        v[o] = embt[(size_t)o * N + img];
        m = fmaxf(m, v[o]);
    }
    float s = 0.f;
    #pragma unroll
    for (int o = 0; o < 64; ++o) {
        v[o] = __expf(v[o] - m);
        s += v[o];
    }
    float inv = __frcp_rn(s);
    #pragma unroll
    for (int o = 0; o < 64; o += 4) {
        float4 r;
        r.x = fabsf(v[o+0] * inv - embt[(size_t)(o+0) * N] * 0.2f);
        r.y = fabsf(v[o+1] * inv - embt[(size_t)(o+1) * N] * 0.2f);
        r.z = fabsf(v[o+2] * inv - embt[(size_t)(o+2) * N] * 0.2f);
        r.w = fabsf(v[o+3] * inv - embt[(size_t)(o+3) * N] * 0.2f);
        *(float4*)&out[(size_t)img * 64 + o] = r;
    }
}

extern "C" void kernel_launch(void* const* d_in, const int* in_sizes, int n_in,
                              void* d_out, int out_size, void* d_ws, size_t ws_size,
                              hipStream_t stream)
{
    const float* x   = (const float*)d_in[0];
    const float* c1w = (const float*)d_in[1];
    const float* c1b = (const float*)d_in[2];
    const float* c2w = (const float*)d_in[3];
    const float* c2b = (const float*)d_in[4];
    const float* f1w = (const float*)d_in[5];
    const float* f1b = (const float*)d_in[6];
    const float* f2w = (const float*)d_in[7];
    const float* f2b = (const float*)d_in[8];
    const float* f3w = (const float*)d_in[9];
    const float* f3b = (const float*)d_in[10];
    float* out = (float*)d_out;

    const int N = in_sizes[0] / 784;          // 20480
    float* base = (float*)d_ws;

    // Region A: xt[1024][nc] -> reused as ht[400][nc]
    // Region B: p1p[1176][nc] (packed) -> reused as a1t[120][nc]+a2t[84][nc]
    // embt[64][N] persistent.  bytes = 8800nc + 256N
    int c = 40;
    const int cands[] = {1, 2, 4, 5, 8, 10, 20, 40};
    for (int k = 0; k < 8; ++k) {
        int cd = cands[k];
        if (N % cd) continue;
        int ncq = N / cd;
        if (ncq % 512) continue;
        size_t need = (size_t)8800 * ncq + (size_t)256 * N;
        if (need <= ws_size) { c = cd; break; }
    }
    const int nc = N / c;

    float*    xt   = base;                        // [1024][nc]
    uint32_t* p1p  = (uint32_t*)(base + (size_t)1024 * nc);  // [1176][nc]
    float*    ht_  = base;                        // [400][nc] (over xt)
    float*    a1t  = (float*)p1p;                 // [120][nc] (over p1p)
    float*    a2t  = (float*)p1p + (size_t)120 * nc;  // [84][nc]
    float*    embt = base + (size_t)2200 * nc;    // [64][N]

    for (int k = 0; k < c; ++k) {
        int n0 = k * nc;
        transpose_x<<<dim3(16, nc / 64), 256, 0, stream>>>(
            x + (size_t)n0 * 784, xt, nc);
        conv1_bt<<<392 * (nc / 512), 256, 0, stream>>>(
            xt, c1w, c1b, p1p, nc);
        conv2_mfma<<<25 * (nc / 256), 256, 0, stream>>>(
            p1p, c2w, c2b, ht_, nc);
        fc1_bt<<<15 * (nc / 512), 256, 0, stream>>>(
            ht_, f1w, f1b, a1t, nc);
        fc2_bt<<<12 * (nc / 512), 256, 0, stream>>>(
            a1t, f2w, f2b, a2t, nc);
        fc3_bt<<<8 * (nc / 512), 256, 0, stream>>>(
            a2t, f3w, f3b, embt, nc, N, n0);
    }
    proto_head_t<<<N / 256, 256, 0, stream>>>(embt, out, N);
}